// Round 4
// baseline (1932.022 us; speedup 1.0000x reference)
//
#include <hip/hip_runtime.h>

// Problem constants (MotionDiscreteAE): B=32, N=2048, D=512, S=2, K=1024, DS=256
#define BN_   65536   // B*N
#define K_    1024
#define DS_   256
#define D_    512
#define TM    64      // m-vectors per block (argmin kernel); lane == m

typedef float f32x16 __attribute__((ext_vector_type(16)));

// ---------------------------------------------------------------------------
// Kernel 0: w_sq[s*K + k] = sum_d W[s][k][d]^2  (fp32 chunked; error ~1e-10,
// negligible vs the 1.5e-5 quantization grid of (x_sq + w_sq)).
// ---------------------------------------------------------------------------
__global__ __launch_bounds__(256)
void wsq_kernel(const float* __restrict__ W, float* __restrict__ wsq) {
  const int k = blockIdx.x * 256 + threadIdx.x;  // 0..2047
  const float4* row = (const float4*)(W + (size_t)k * DS_);
  float s0 = 0.f, s1 = 0.f, s2 = 0.f, s3 = 0.f;
#pragma unroll
  for (int i = 0; i < DS_ / 4; ++i) {
    const float4 v = row[i];
    s0 = fmaf(v.x, v.x, s0);
    s1 = fmaf(v.y, v.y, s1);
    s2 = fmaf(v.z, v.z, s2);
    s3 = fmaf(v.w, v.w, s3);
  }
  wsq[k] = (s0 + s1) + (s2 + s3);
}

// ---------------------------------------------------------------------------
// Kernel 0b: xsq[s*BN + m] = np.sum(x*x, -1) BIT-EXACT numpy-pairwise fp32.
// numpy pairwise_sum for n=256 contiguous: pair(a[0:128]) + pair(a[128:256]);
// each 128-block: r[j]=a[j]^2; for t=1..15: r[j]+=a[8t+j]^2 (j asc inner);
// combine ((r0+r1)+(r2+r3))+((r4+r5)+(r6+r7)). No FMA anywhere.
// float4 loads preserve the exact element->r[j] mapping and add order.
// ---------------------------------------------------------------------------
__global__ __launch_bounds__(256)
void xsq_kernel(const float* __restrict__ h, float* __restrict__ xsq) {
  const int idx = blockIdx.x * 256 + threadIdx.x;  // 0..131071
  const int s = idx >> 16;
  const int m = idx & 0xFFFF;
  const float4* x = (const float4*)(h + (size_t)m * D_ + s * DS_);
  float blk[2];
#pragma unroll
  for (int b = 0; b < 2; ++b) {
    float r[8];
    {  // t = 0: a[0..7]
      const float4 v0 = x[b * 32 + 0];
      const float4 v1 = x[b * 32 + 1];
      r[0] = __fmul_rn(v0.x, v0.x); r[1] = __fmul_rn(v0.y, v0.y);
      r[2] = __fmul_rn(v0.z, v0.z); r[3] = __fmul_rn(v0.w, v0.w);
      r[4] = __fmul_rn(v1.x, v1.x); r[5] = __fmul_rn(v1.y, v1.y);
      r[6] = __fmul_rn(v1.z, v1.z); r[7] = __fmul_rn(v1.w, v1.w);
    }
    for (int t = 1; t < 16; ++t) {  // a[t*8 + j], j = 0..7 ascending
      const float4 v0 = x[b * 32 + 2 * t];
      const float4 v1 = x[b * 32 + 2 * t + 1];
      r[0] = __fadd_rn(r[0], __fmul_rn(v0.x, v0.x));
      r[1] = __fadd_rn(r[1], __fmul_rn(v0.y, v0.y));
      r[2] = __fadd_rn(r[2], __fmul_rn(v0.z, v0.z));
      r[3] = __fadd_rn(r[3], __fmul_rn(v0.w, v0.w));
      r[4] = __fadd_rn(r[4], __fmul_rn(v1.x, v1.x));
      r[5] = __fadd_rn(r[5], __fmul_rn(v1.y, v1.y));
      r[6] = __fadd_rn(r[6], __fmul_rn(v1.z, v1.z));
      r[7] = __fadd_rn(r[7], __fmul_rn(v1.w, v1.w));
    }
    const float s01 = __fadd_rn(r[0], r[1]);
    const float s23 = __fadd_rn(r[2], r[3]);
    const float s45 = __fadd_rn(r[4], r[5]);
    const float s67 = __fadd_rn(r[6], r[7]);
    blk[b] = __fadd_rn(__fadd_rn(s01, s23), __fadd_rn(s45, s67));
  }
  xsq[idx] = __fadd_rn(blk[0], blk[1]);
}

// ---------------------------------------------------------------------------
// Kernel 0c: Wt[s][d][k] = W[s][k][d]  (2 MiB transpose; tiled, coalesced
// both sides). Gives the argmin kernel contiguous [d][k..k+15] rows so W can
// be read wave-uniformly as s_load_dwordx16 (SGPR broadcast).
// ---------------------------------------------------------------------------
__global__ __launch_bounds__(256)
void wt_kernel(const float* __restrict__ W, float* __restrict__ Wt) {
  __shared__ float t[32][33];
  const int s  = blockIdx.z;
  const int kb = blockIdx.x * 32;
  const int db = blockIdx.y * 32;
  const int tx = threadIdx.x & 31;
  const int ty = threadIdx.x >> 5;  // 0..7
  const float* Ws  = W  + (size_t)s * K_ * DS_;
  float*       Wts = Wt + (size_t)s * DS_ * K_;
#pragma unroll
  for (int i = 0; i < 4; ++i) {
    const int k = ty + i * 8;  // 0..31
    t[k][tx] = Ws[(size_t)(kb + k) * DS_ + db + tx];
  }
  __syncthreads();
#pragma unroll
  for (int i = 0; i < 4; ++i) {
    const int d = ty + i * 8;  // 0..31
    Wts[(size_t)(db + d) * K_ + kb + tx] = t[tx][d];
  }
}

// ---------------------------------------------------------------------------
// Kernel 1: per (slice s, vector m):
//   argmin_k  D_k = fl32( fl32(xsq_m + wsq_k) - 2*dot(x_m, w_k) )
// Bit-identical distance math to R4: dot = sum over 8 chunks (dc=0..7
// ascending) of 32-d FMA chains (dd ascending), acc += acct per chunk,
// fold with strict-< + lexicographic quarter-merge == np.argmin.
// R8 structure (perf only):
//   lane == m (64 m per block), wave == k-quarter (256 k).
//   W operand is wave-uniform -> s_load_dwordx16 into SGPRs (SMEM pipe,
//     zero LDS instructions, zero VGPRs for w).
//   x from LDS: xs[m][d] row-per-lane, granule-XOR-swizzled; ONE
//     ds_read_b128 per 4 d per wave (vs R4's 3 per 1 d) -> LDS pipe at
//     ~35% while FMA issue ~90%.
//   acc[16]+acct[16]+temps ~ 60 VGPR -> no spill, 2 blocks/CU (LDS 64 KiB),
//   main loop barrier-free (xs staged once, read-only).
// ---------------------------------------------------------------------------
__global__ __launch_bounds__(256, 2)
void argmin_kernel(const float* __restrict__ h, const float* __restrict__ Wt,
                   const float* __restrict__ wsq, const float* __restrict__ xsq,
                   int* __restrict__ ids, float* __restrict__ partials) {
  __shared__ float xs[TM][DS_];   // 64 KiB, [m][d], granule-swizzled
  const int tid  = threadIdx.x;
  const int lane = tid & 63;      // = m within tile
  const int wid  = tid >> 6;      // wave id = k-quarter
  const int m0   = blockIdx.x * TM;
  const int s    = blockIdx.y;

  const float* __restrict__ Wts   = Wt  + (size_t)s * DS_ * K_;
  const float* __restrict__ wsq_s = wsq + s * K_;

  // ---- stage x tile once: xs[m][granule g] stored at g' = g ^ m ----
  {
    const int m     = tid & 63;
    const int gbase = (tid >> 6) * 16;  // 16 granules (of 4 floats) each
    const float* xrow = h + (size_t)(m0 + m) * D_ + s * DS_;
    char* xsb = (char*)&xs[0][0];
#pragma unroll
    for (int it = 0; it < 16; ++it) {
      const int g = gbase + it;
      const float4 v = *(const float4*)(xrow + g * 4);
      *(float4*)(xsb + m * 1024 + (((g ^ m) & 63) << 4)) = v;
    }
  }
  __syncthreads();  // xs ready; no further barriers until the merge

  // k-quarter base, forced wave-uniform (SGPR)
  const int kqb = __builtin_amdgcn_readfirstlane(wid << 8);  // wid*256

  // per-m oracle x_sq (bit-exact numpy value); lane == m
  const float Xq = xsq[s * BN_ + m0 + lane];

  float bestv = 3.4e38f;
  int   besti = 0x7fffffff;

  const char* xsb = (const char*)&xs[0][0];
  const int rowoff = lane * 1024;

  float acc[16];
#pragma unroll
  for (int j = 0; j < 16; ++j) acc[j] = 0.f;

  // ---- 16 k-subtiles of 16; per subtile: 8 chunks of 32 d ----
#pragma unroll 1
  for (int kk = 0; kk < 16; ++kk) {
    const int kq = kqb + kk * 16;  // uniform
#pragma unroll 1
    for (int dc = 0; dc < 8; ++dc) {
      float acct[16];
#pragma unroll
      for (int j = 0; j < 16; ++j) acct[j] = 0.f;
#pragma unroll
      for (int gq = 0; gq < 8; ++gq) {  // granule = 4 consecutive d
        const int g = dc * 8 + gq;
        const float4 xq =
            *(const float4*)(xsb + rowoff + (((g ^ lane) & 63) << 4));
        const float xv[4] = {xq.x, xq.y, xq.z, xq.w};
#pragma unroll
        for (int e = 0; e < 4; ++e) {  // dd = gq*4+e ascending -> exact chain
          const int d = g * 4 + e;
          const f32x16 w = *(const f32x16*)(Wts + (size_t)d * K_ + kq);
#pragma unroll
          for (int j = 0; j < 16; ++j)
            acct[j] = fmaf(xv[e], w[j], acct[j]);
        }
      }
#pragma unroll
      for (int j = 0; j < 16; ++j) acc[j] += acct[j];
    }
    // fold 16 candidates (k ascending within lane => strict < keeps lowest)
    const f32x16 wq = *(const f32x16*)(wsq_s + kq);
#pragma unroll
    for (int j = 0; j < 16; ++j) {
      const float t1 = __fadd_rn(Xq, wq[j]);
      const float dv = __fsub_rn(t1, 2.0f * acc[j]);
      if (dv < bestv) { bestv = dv; besti = kq + j; }
      acc[j] = 0.f;
    }
  }

  // ---- merge 4 quarters (ascending k): lexicographic == np.argmin ----
  __syncthreads();  // xs free for candidate overlay
  float* candv = &xs[0][0];               // 256 floats
  int*   candi = (int*)(&xs[0][0] + 256); // 256 ints
  candv[wid * 64 + lane] = bestv;
  candi[wid * 64 + lane] = besti;
  __syncthreads();
  if (tid < TM) {
    float bv = 3.4e38f;
    int   bi = 0x7fffffff;
#pragma unroll
    for (int t = 0; t < 4; ++t) {  // quarters ascending => k ascending
      const float v = candv[t * 64 + tid];
      const int   c = candi[t * 64 + tid];
      if (v < bv || (v == bv && c < bi)) { bv = v; bi = c; }
    }
    ids[s * BN_ + m0 + tid] = bi;
    // VQ-loss partial: bv == quantized ||x - w_best||^2
    float v = bv;
#pragma unroll
    for (int off = 32; off > 0; off >>= 1) v += __shfl_down(v, off);
    if (tid == 0) partials[blockIdx.y * 1024 + blockIdx.x] = v;
  }
}

// ---------------------------------------------------------------------------
// Kernel 2: z[m][d] = W[s][ids[s][m]][d mod 256];  out_ids[m] = id0 + 1024*id1
// ---------------------------------------------------------------------------
__global__ __launch_bounds__(256)
void gather_kernel(const float* __restrict__ W, const int* __restrict__ ids,
                   float* __restrict__ out) {
  const int tid = threadIdx.x;
  float* out_ids = out + (size_t)BN_ * D_;
#pragma unroll
  for (int it = 0; it < 4; ++it) {
    const size_t i4 = (size_t)it * 2097152 + (size_t)blockIdx.x * 256 + tid;
    const size_t e  = i4 * 4;               // element index into [BN, 512]
    const int m  = (int)(e >> 9);
    const int d  = (int)(e & 511);
    const int s  = d >> 8;
    const int dd = d & 255;
    const int id = ids[s * BN_ + m];
    const float4 z = *(const float4*)(W + ((size_t)(s * K_ + id)) * DS_ + dd);
    *(float4*)(out + e) = z;
    if (d == 0) {  // one thread per m writes the packed id (as float value)
      const int id1 = ids[BN_ + m];
      out_ids[m] = (float)(id + (id1 << 10));
    }
  }
}

// ---------------------------------------------------------------------------
// Kernel 3: vq_total = 1.25 * sum(partials) / (BN*DS)
// ---------------------------------------------------------------------------
__global__ __launch_bounds__(256)
void finalize_kernel(const float* __restrict__ partials,
                     float* __restrict__ out_vq) {
  __shared__ float red[256];
  const int tid = threadIdx.x;
  float s = 0.f;
  for (int i = tid; i < 2048; i += 256) s += partials[i];
  red[tid] = s;
  __syncthreads();
  for (int off = 128; off > 0; off >>= 1) {
    if (tid < off) red[tid] += red[tid + off];
    __syncthreads();
  }
  if (tid == 0) out_vq[0] = red[0] * (1.25f / 16777216.f);
}

// ---------------------------------------------------------------------------
extern "C" void kernel_launch(void* const* d_in, const int* in_sizes, int n_in,
                              void* d_out, int out_size, void* d_ws,
                              size_t ws_size, hipStream_t stream) {
  const float* h = (const float*)d_in[0];  // [BN, 512]
  const float* W = (const float*)d_in[1];  // [2, 1024, 256]
  float* out  = (float*)d_out;             // z | ids(as float) | vq_total
  float* wsf  = (float*)d_ws;
  float* wsq      = wsf;                   // 2048 floats
  float* partials = wsf + 2048;            // 2048 floats
  int*   ids      = (int*)(wsf + 4096);    // 131072 ints
  float* xsq      = wsf + 4096 + 131072;   // 131072 floats
  // Wt needs 524288 floats (2 MiB). Prefer workspace; else use the z-region
  // of `out` as scratch (stream-ordered: wt_kernel writes it, argmin reads
  // it, gather_kernel fully overwrites it afterwards).
  const size_t wt_off = 4096 + 131072 + 131072;
  float* Wt = (ws_size >= (wt_off + 524288) * sizeof(float))
                  ? (wsf + wt_off) : out;

  wsq_kernel<<<8, 256, 0, stream>>>(W, wsq);
  xsq_kernel<<<512, 256, 0, stream>>>(h, xsq);
  wt_kernel<<<dim3(32, 8, 2), 256, 0, stream>>>(W, Wt);
  argmin_kernel<<<dim3(1024, 2), 256, 0, stream>>>(h, Wt, wsq, xsq, ids,
                                                   partials);
  gather_kernel<<<8192, 256, 0, stream>>>(W, ids, out);
  finalize_kernel<<<1, 256, 0, stream>>>(partials,
                                         out + (size_t)BN_ * D_ + BN_);
}